// Round 3
// baseline (173.782 us; speedup 1.0000x reference)
//
#include <hip/hip_runtime.h>
#include <math.h>

#define T_MAX 11  // MAX_TURNS from the reference

// ---------------------------------------------------------------------------
// Kernel 1: probs + per-row weights. Grid = S blocks, one wave per valid row.
// float4 dot loads (3 per lane). ~3 us.
// ---------------------------------------------------------------------------
__global__ __launch_bounds__(256) void k_probs(
    const float* __restrict__ hist,       // [rows, hidden]
    const float* __restrict__ W,          // [hidden]
    const float* __restrict__ b,          // [1]
    const int*   __restrict__ slice_mask, // [>=S]
    int S, int rows, int hidden,
    float* __restrict__ probs_out,        // [S, T_MAX]
    float* __restrict__ w_ws,             // [rows]
    int*   __restrict__ ns_ws,            // [S]
    int*   __restrict__ off_ws)           // [S]
{
    __shared__ float s_exp[T_MAX];
    __shared__ float s_wk[T_MAX];
    __shared__ int   s_off, s_n;

    const int sidx = blockIdx.x;
    const int tid  = threadIdx.x;
    const int lane = tid & 63;
    const int wave = tid >> 6;

    if (tid == 0) {
        int acc = 0, n = 0;
        for (int i = 0; i < S; ++i) {
            const int v = slice_mask[i];
            if (i < sidx) acc += v;
            if (i == sidx) n = v;
        }
        s_off = acc; s_n = n;
        ns_ws[sidx] = n; off_ws[sidx] = acc;
    }
    __syncthreads();

    const int o = s_off;
    const int n = s_n;
    const int h4 = hidden >> 2;           // 192 float4s
    const float4* W4 = (const float4*)W;

    for (int k = wave; k < n; k += 4) {
        int idx = min(o + k, rows - 1);
        const float4* hrow = (const float4*)(hist + (size_t)idx * hidden);
        float acc = 0.0f;
        for (int j = lane; j < h4; j += 64) {
            const float4 hv = hrow[j];
            const float4 wv = W4[j];
            acc += hv.x*wv.x + hv.y*wv.y + hv.z*wv.z + hv.w*wv.w;
        }
        #pragma unroll
        for (int d = 32; d > 0; d >>= 1)
            acc += __shfl_down(acc, d);
        if (lane == 0) s_exp[k] = expf(acc + b[0]);
    }
    __syncthreads();

    if (tid == 0) {
        float sum = 0.0f;
        for (int k = 0; k < n; ++k) sum += s_exp[k];
        const float inv = 1.0f / sum;
        for (int k = 0; k < n; ++k) {
            const float wk = s_exp[k] * inv;
            s_wk[k] = wk;
            w_ws[o + k] = wk;
        }
    }
    __syncthreads();

    if (tid < T_MAX) {
        const int pad = T_MAX - n;
        probs_out[sidx * T_MAX + tid] = (tid >= pad) ? s_wk[tid - pad] : 0.0f;
    }
}

// ---------------------------------------------------------------------------
// Kernel 2: pure streaming weighted segment-sum. 4 f4 columns per thread
// (independent loads -> MLP up to 4*n), near-zero prologue.
// Column space per segment: [0, bert_cols4) = bert, [bert_cols4, total) = mtl.
// ---------------------------------------------------------------------------
__global__ __launch_bounds__(256) void k_segsum(
    const float4* __restrict__ bert,
    const float4* __restrict__ mtl,
    const float*  __restrict__ w_ws,
    const int*    __restrict__ ns_ws,
    const int*    __restrict__ off_ws,
    int nchunks, int bert_cols4, int mtl_cols4, int rows,
    float4* __restrict__ out_bert,
    float4* __restrict__ out_mtl)
{
    __shared__ float s_w[T_MAX];
    __shared__ int   s_o, s_n;

    const int sidx  = blockIdx.x / nchunks;
    const int chunk = blockIdx.x - sidx * nchunks;
    const int tid   = threadIdx.x;

    if (tid == 0) { s_o = off_ws[sidx]; s_n = ns_ws[sidx]; }
    __syncthreads();
    if (tid < s_n) s_w[tid] = w_ws[s_o + tid];
    __syncthreads();

    const int o = s_o;
    const int n = s_n;
    const int total_f4 = bert_cols4 + mtl_cols4;
    const int base = chunk * 1024 + tid;

    float4 acc[4];
    #pragma unroll
    for (int j = 0; j < 4; ++j) acc[j] = make_float4(0.f, 0.f, 0.f, 0.f);

    for (int k = 0; k < n; ++k) {
        const float wk = s_w[k];
        const int r = min(o + k, rows - 1);
        const float4* brow = bert + (size_t)r * bert_cols4;
        const float4* mrow = mtl  + (size_t)r * mtl_cols4;
        #pragma unroll
        for (int j = 0; j < 4; ++j) {
            const int i = base + j * 256;
            if (i < total_f4) {
                const float4 v = (i < bert_cols4) ? brow[i]
                                                  : mrow[i - bert_cols4];
                acc[j].x += wk * v.x; acc[j].y += wk * v.y;
                acc[j].z += wk * v.z; acc[j].w += wk * v.w;
            }
        }
    }

    #pragma unroll
    for (int j = 0; j < 4; ++j) {
        const int i = base + j * 256;
        if (i < total_f4) {
            if (i < bert_cols4)
                out_bert[(size_t)sidx * bert_cols4 + i] = acc[j];
            else
                out_mtl[(size_t)sidx * mtl_cols4 + (i - bert_cols4)] = acc[j];
        }
    }
}

extern "C" void kernel_launch(void* const* d_in, const int* in_sizes, int n_in,
                              void* d_out, int out_size, void* d_ws, size_t ws_size,
                              hipStream_t stream) {
    const float* bert = (const float*)d_in[0];
    const float* hist = (const float*)d_in[1];
    const float* mtl  = (const float*)d_in[2];
    const float* W    = (const float*)d_in[3];
    const float* b    = (const float*)d_in[4];
    const int* slice_mask = (const int*)d_in[5];

    const int hidden = in_sizes[3];                       // 768
    const int rows   = in_sizes[1] / hidden;              // 64
    const int seq    = in_sizes[0] / (rows * hidden);     // 512
    const int S = out_size / (seq * hidden + hidden + T_MAX);   // 16

    float* out       = (float*)d_out;
    float* out_bert  = out;
    float* out_mtl   = out_bert + (size_t)S * seq * hidden;
    float* out_probs = out_mtl  + (size_t)S * hidden;

    // workspace: w[rows] floats, then (256B-aligned) ns[S], off[S]
    char*  wsb   = (char*)d_ws;
    float* w_ws  = (float*)wsb;
    size_t ofs   = (((size_t)rows * sizeof(float)) + 255) & ~(size_t)255;
    int*   ns_ws  = (int*)(wsb + ofs);
    int*   off_ws = ns_ws + S;

    k_probs<<<S, 256, 0, stream>>>(hist, W, b, slice_mask, S, rows, hidden,
                                   out_probs, w_ws, ns_ws, off_ws);

    const int bert_cols4 = seq * hidden / 4;   // 98304
    const int mtl_cols4  = hidden / 4;         // 192
    const int total_f4   = bert_cols4 + mtl_cols4;   // 98496
    const int nchunks    = (total_f4 + 1023) / 1024; // 97
    const int grid       = S * nchunks;              // 1552

    k_segsum<<<grid, 256, 0, stream>>>((const float4*)bert, (const float4*)mtl,
                                       w_ws, ns_ws, off_ws,
                                       nchunks, bert_cols4, mtl_cols4, rows,
                                       (float4*)out_bert, (float4*)out_mtl);
}

// Round 5
// 160.649 us; speedup vs baseline: 1.0818x; 1.0818x over previous
//
#include <hip/hip_runtime.h>
#include <math.h>

#define T_MAX 11  // MAX_TURNS from the reference

typedef float f4 __attribute__((ext_vector_type(4)));  // nontemporal-compatible

// ---------------------------------------------------------------------------
// Kernel 1: probs + per-row weights + mtl segment-sum (tiny). Grid = S blocks.
// One wave per valid history row dot-product; then this block's mtl output row.
// ---------------------------------------------------------------------------
__global__ __launch_bounds__(256) void k_probs(
    const float*  __restrict__ hist,       // [rows, hidden]
    const float4* __restrict__ mtl4,       // [rows, hidden/4]
    const float*  __restrict__ W,          // [hidden]
    const float*  __restrict__ b,          // [1]
    const int*    __restrict__ slice_mask, // [>=S]
    int S, int rows, int hidden,
    float*  __restrict__ probs_out,        // [S, T_MAX]
    float4* __restrict__ out_mtl,          // [S, hidden/4]
    float*  __restrict__ w_ws,             // [rows]
    int*    __restrict__ ns_ws,            // [S]
    int*    __restrict__ off_ws)           // [S]
{
    __shared__ float s_exp[64];
    __shared__ float s_wk[64];
    __shared__ int   s_off, s_n;

    const int sidx = blockIdx.x;
    const int tid  = threadIdx.x;
    const int lane = tid & 63;
    const int wave = tid >> 6;

    if (tid == 0) {
        int acc = 0, n = 0;
        for (int i = 0; i < S; ++i) {
            const int v = slice_mask[i];
            if (i < sidx) acc += v;
            if (i == sidx) n = v;
        }
        s_off = acc; s_n = n;
        ns_ws[sidx] = n; off_ws[sidx] = acc;
    }
    __syncthreads();

    const int o  = s_off;
    const int n  = s_n;
    const int h4 = hidden >> 2;
    const float4* W4 = (const float4*)W;

    for (int k = wave; k < n; k += 4) {
        const int idx = min(o + k, rows - 1);
        const float4* hrow = (const float4*)(hist + (size_t)idx * hidden);
        float acc = 0.0f;
        for (int j = lane; j < h4; j += 64) {
            const float4 hv = hrow[j];
            const float4 wv = W4[j];
            acc += hv.x*wv.x + hv.y*wv.y + hv.z*wv.z + hv.w*wv.w;
        }
        #pragma unroll
        for (int d = 32; d > 0; d >>= 1)
            acc += __shfl_down(acc, d);
        if (lane == 0) s_exp[k] = expf(acc + b[0]);
    }
    __syncthreads();

    if (tid == 0) {
        float sum = 0.0f;
        for (int k = 0; k < n; ++k) sum += s_exp[k];
        const float inv = 1.0f / sum;
        for (int k = 0; k < n; ++k) {
            const float wk = s_exp[k] * inv;
            s_wk[k] = wk;
            w_ws[o + k] = wk;
        }
    }
    __syncthreads();

    if (tid < T_MAX) {
        const int pad = T_MAX - n;
        probs_out[sidx * T_MAX + tid] = (tid >= pad && tid - pad < n)
                                        ? s_wk[tid - pad] : 0.0f;
    }

    // mtl segment-sum for this segment (hidden/4 = 192 float4 columns)
    for (int i = tid; i < h4; i += 256) {
        float4 acc = {0.f, 0.f, 0.f, 0.f};
        for (int k = 0; k < n; ++k) {
            const float wk = s_wk[k];
            const int r = min(o + k, rows - 1);
            const float4 v = mtl4[(size_t)r * h4 + i];
            acc.x += wk * v.x; acc.y += wk * v.y;
            acc.z += wk * v.z; acc.w += wk * v.w;
        }
        out_mtl[(size_t)sidx * h4 + i] = acc;
    }
}

// ---------------------------------------------------------------------------
// Kernel 2: pure bert weighted segment-sum. Branch-free n==4 fast path:
// all 16 independent f4 loads issued before any FMA (16 KB per wave in
// flight -> one latency exposure per wave, not one per k-iteration).
// Non-temporal: every byte read once, written once.
// ---------------------------------------------------------------------------
__global__ __launch_bounds__(256) void k_segsum(
    const f4* __restrict__ bert,
    const float*  __restrict__ w_ws,
    const int*    __restrict__ ns_ws,
    const int*    __restrict__ off_ws,
    int nchunks, int bert_cols4, int rows,
    f4* __restrict__ out_bert)
{
    __shared__ float s_w[64];
    __shared__ int   s_o, s_n;

    const int sidx  = blockIdx.x / nchunks;
    const int chunk = blockIdx.x - sidx * nchunks;
    const int tid   = threadIdx.x;

    if (tid == 0) { s_o = off_ws[sidx]; s_n = ns_ws[sidx]; }
    __syncthreads();
    if (tid < s_n && tid < 64) s_w[tid] = w_ws[s_o + tid];
    __syncthreads();

    const int o = s_o, n = s_n;
    const int base = chunk * 1024 + tid;
    f4* outp = out_bert + (size_t)sidx * bert_cols4;

    if (n == 4) {
        const float w0 = s_w[0], w1 = s_w[1], w2 = s_w[2], w3 = s_w[3];
        const f4* r0 = bert + (size_t)min(o + 0, rows - 1) * bert_cols4;
        const f4* r1 = bert + (size_t)min(o + 1, rows - 1) * bert_cols4;
        const f4* r2 = bert + (size_t)min(o + 2, rows - 1) * bert_cols4;
        const f4* r3 = bert + (size_t)min(o + 3, rows - 1) * bert_cols4;

        f4 v[4][4];
        bool ok[4];
        #pragma unroll
        for (int j = 0; j < 4; ++j) {
            const int i = base + j * 256;
            ok[j] = (i < bert_cols4);
            if (ok[j]) {
                v[j][0] = __builtin_nontemporal_load(&r0[i]);
                v[j][1] = __builtin_nontemporal_load(&r1[i]);
                v[j][2] = __builtin_nontemporal_load(&r2[i]);
                v[j][3] = __builtin_nontemporal_load(&r3[i]);
            }
        }
        #pragma unroll
        for (int j = 0; j < 4; ++j) {
            if (ok[j]) {
                const int i = base + j * 256;
                f4 acc = w0 * v[j][0] + w1 * v[j][1] + w2 * v[j][2] + w3 * v[j][3];
                __builtin_nontemporal_store(acc, &outp[i]);
            }
        }
    } else {
        #pragma unroll
        for (int j = 0; j < 4; ++j) {
            const int i = base + j * 256;
            if (i < bert_cols4) {
                f4 acc = {0.f, 0.f, 0.f, 0.f};
                for (int k = 0; k < n; ++k) {
                    const float wk = s_w[k & 63];
                    const int r = min(o + k, rows - 1);
                    const f4 vv = bert[(size_t)r * bert_cols4 + i];
                    acc += wk * vv;
                }
                __builtin_nontemporal_store(acc, &outp[i]);
            }
        }
    }
}

extern "C" void kernel_launch(void* const* d_in, const int* in_sizes, int n_in,
                              void* d_out, int out_size, void* d_ws, size_t ws_size,
                              hipStream_t stream) {
    const float* bert = (const float*)d_in[0];
    const float* hist = (const float*)d_in[1];
    const float* mtl  = (const float*)d_in[2];
    const float* W    = (const float*)d_in[3];
    const float* b    = (const float*)d_in[4];
    const int* slice_mask = (const int*)d_in[5];

    const int hidden = in_sizes[3];                       // 768
    const int rows   = in_sizes[1] / hidden;              // 64
    const int seq    = in_sizes[0] / (rows * hidden);     // 512
    const int S = out_size / (seq * hidden + hidden + T_MAX);   // 16

    float* out       = (float*)d_out;
    float* out_bert  = out;
    float* out_mtl   = out_bert + (size_t)S * seq * hidden;
    float* out_probs = out_mtl  + (size_t)S * hidden;

    // workspace: w[rows] floats, then (256B-aligned) ns[S], off[S]
    char*  wsb   = (char*)d_ws;
    float* w_ws  = (float*)wsb;
    size_t ofs   = (((size_t)rows * sizeof(float)) + 255) & ~(size_t)255;
    int*   ns_ws  = (int*)(wsb + ofs);
    int*   off_ws = ns_ws + S;

    k_probs<<<S, 256, 0, stream>>>(hist, (const float4*)mtl, W, b, slice_mask,
                                   S, rows, hidden,
                                   out_probs, (float4*)out_mtl,
                                   w_ws, ns_ws, off_ws);

    const int bert_cols4 = seq * hidden / 4;              // 98304
    const int chunk_f4   = 1024;                          // 4 f4 per thread
    const int nchunks    = (bert_cols4 + chunk_f4 - 1) / chunk_f4;  // 96
    const int grid       = S * nchunks;                   // 1536

    k_segsum<<<grid, 256, 0, stream>>>((const f4*)bert,
                                       w_ws, ns_ws, off_ws,
                                       nchunks, bert_cols4, rows,
                                       (f4*)out_bert);
}